// Round 2
// baseline (1525.251 us; speedup 1.0000x reference)
//
#include <hip/hip_runtime.h>
#include <math.h>

#define NJ 128
#define HH 512
#define WW 512
#define HF 1024
#define WF 1024
#define FEPS 1e-7f

// param layout offsets (in floats) inside `par`
#define P_MMX 0
#define P_MMY 128
#define P_IA  256
#define P_IB2 384
#define P_IC  512
#define P_V00 640
#define P_V10 768
#define P_V01 896
#define P_V11 1024
#define P_LS0 1152
#define P_LS1 1280
#define P_TOT 1408

// ---------------------------------------------------------------- K1: per-Gaussian params
__global__ void k_setup(const float* __restrict__ mu, const float* __restrict__ sigma,
                        float* __restrict__ par, unsigned* __restrict__ gm,
                        int* __restrict__ cnt) {
    int j = threadIdx.x;
    if (j >= NJ) return;
    float a = sigma[j * 4 + 0];
    float b = sigma[j * 4 + 1];
    float c = sigma[j * 4 + 3];
    // 2x2 symmetric eigendecomposition, ascending order (matches jnp.linalg.eigh)
    float mean = 0.5f * (a + c);
    float diff = 0.5f * (a - c);
    float disc = sqrtf(diff * diff + b * b);
    float l0 = mean - disc;   // smaller
    float l1 = mean + disc;   // larger
    // eigenvector for l1, picked for numerical robustness; sign is irrelevant
    float ux, uy;
    if (diff >= 0.f) { ux = diff + disc; uy = b; }
    else             { ux = b;           uy = disc - diff; }
    float nn = sqrtf(ux * ux + uy * uy);
    if (nn > 0.f) { ux /= nn; uy /= nn; } else { ux = 1.f; uy = 0.f; }
    // V columns: col0 <-> l0, col1 <-> l1
    float V00 = -uy, V10 = ux;   // column 0
    float V01 =  ux, V11 = uy;   // column 1
    // Lsc = Ld / sqrt(Ld0*Ld1) * 4096 ; sg = V diag(Lsc) V^T / 4
    float gmean = sqrtf(l0 * l1);
    float lsc0 = l0 / gmean * 4096.f;
    float lsc1 = l1 / gmean * 4096.f;
    float s00 = (V00 * V00 * lsc0 + V01 * V01 * lsc1) * 0.25f;
    float s01 = (V00 * V10 * lsc0 + V01 * V11 * lsc1) * 0.25f;
    float s11 = (V10 * V10 * lsc0 + V11 * V11 * lsc1) * 0.25f;
    float det = s00 * s11 - s01 * s01;
    float ia =  s11 / det;
    float ib = -s01 / det;
    float ic =  s00 / det;
    par[P_MMX + j] = rintf(mu[j * 2 + 0] * 0.5f);   // jnp.round = ties-to-even = rintf
    par[P_MMY + j] = rintf(mu[j * 2 + 1] * 0.5f);
    par[P_IA  + j] = ia;
    par[P_IB2 + j] = 2.f * ib;
    par[P_IC  + j] = ic;
    par[P_V00 + j] = V00; par[P_V10 + j] = V10;
    par[P_V01 + j] = V01; par[P_V11 + j] = V11;
    par[P_LS0 + j] = l0;  par[P_LS1 + j] = l1;
    gm[j] = 0u; gm[NJ + j] = 0u;   // |rot| >= 0, so uint-bit max with init 0 is exact
    cnt[j] = 0;
}

// ---------------------------------------------------------------- K2: half-res argmin maha
__global__ __launch_bounds__(256) void k_vor(const float* __restrict__ par,
                                             float* __restrict__ val,
                                             int* __restrict__ vor) {
    __shared__ float lds[640];
    int tid = threadIdx.x;
    for (int i = tid; i < 640; i += 256) lds[i] = par[i];
    __syncthreads();
    int p = blockIdx.x * 256 + tid;
    int r = p >> 9;     // row -> y
    int c = p & 511;    // col -> x
    const float SCALE = 512.0f / 511.0f;   // linspace(0, 512, 512) step
    float xc = (float)c * SCALE;
    float yr = (float)r * SCALE;
    float best = 3.4e38f;
    int bj = 0;
    #pragma unroll 8
    for (int j = 0; j < NJ; ++j) {
        float dx = xc - lds[P_MMX + j];
        float dy = yr - lds[P_MMY + j];
        float q = lds[P_IA + j] * dx * dx + lds[P_IB2 + j] * dx * dy
                + lds[P_IC + j] * dy * dy;
        if (q < best) { best = q; bj = j; }   // first-index on ties, like argmax(g)
    }
    val[p] = expf(-0.5f * best);
    vor[p] = bj;
}

// ---------------------------------------------------------------- K3: markers + segment max
__global__ __launch_bounds__(256) void k_markers(
        const float* __restrict__ par, const float* __restrict__ val,
        const int* __restrict__ vor, const float* __restrict__ mu,
        const int* __restrict__ label, const float* __restrict__ pos_thres,
        const float* __restrict__ neg_thres,
        unsigned* __restrict__ gm, int* __restrict__ cnt) {
    __shared__ unsigned lm[2 * NJ];
    __shared__ int lflag[NJ];
    int tid = threadIdx.x;
    if (tid < NJ) { lm[tid] = 0u; lm[NJ + tid] = 0u; lflag[tid] = 0; }
    __syncthreads();
    int p = blockIdx.x * 256 + tid;
    int i = p >> 10;    // row (y)
    int j = p & 1023;   // col (x)
    int hv = vor[(i >> 1) * WW + (j >> 1)];
    // exact-integer Laplacian (ones 3x3, center -8, zero-padded) on NN-upsampled vor
    int lap = -8 * hv;
    #pragma unroll
    for (int di = -1; di <= 1; ++di) {
        #pragma unroll
        for (int dj = -1; dj <= 1; ++dj) {
            if (di == 0 && dj == 0) continue;
            int ii = i + di, jj = j + dj;
            if (ii >= 0 && ii < HF && jj >= 0 && jj < WF)
                lap += vor[(ii >> 1) * WW + (jj >> 1)];
        }
    }
    bool ridge = (lap != 0);
    // align-corners bilinear of val: r = idx*511/1023
    float ry = ((float)i * 511.0f) / 1023.0f;
    float rx = ((float)j * 511.0f) / 1023.0f;
    int y0 = (int)floorf(ry); int y1 = min(y0 + 1, 511); float wy = ry - (float)y0;
    int x0 = (int)floorf(rx); int x1 = min(x0 + 1, 511); float wx = rx - (float)x0;
    float top = val[y0 * WW + x0] * (1.f - wx) + val[y0 * WW + x1] * wx;
    float bot = val[y1 * WW + x0] * (1.f - wx) + val[y1 * WW + x1] * wx;
    float vf  = top * (1.f - wy) + bot * wy;
    int cls = label[hv];
    int mk = hv + 1;
    if (vf < pos_thres[cls]) mk = 0;          // order matters: pos -> neg -> ridge
    if (vf < neg_thres[cls]) mk = NJ + 1;
    if (ridge)               mk = NJ + 1;
    if (mk >= 1 && mk <= NJ) {
        int inst = mk - 1;   // == hv here
        float dx = (float)j - mu[inst * 2 + 0];
        float dy = (float)i - mu[inst * 2 + 1];
        float r0 = fabsf(par[P_V00 + inst] * dx + par[P_V10 + inst] * dy);
        float r1 = fabsf(par[P_V01 + inst] * dx + par[P_V11 + inst] * dy);
        atomicMax(&lm[inst],      __float_as_uint(r0));
        atomicMax(&lm[NJ + inst], __float_as_uint(r1));
        lflag[inst] = 1;
    }
    __syncthreads();
    if (tid < NJ && lflag[tid]) {
        atomicMax(&gm[tid],      lm[tid]);
        atomicMax(&gm[NJ + tid], lm[NJ + tid]);
        cnt[tid] = 1;   // only >0 matters
    }
}

// ---------------------------------------------------------------- K4: loss + bottom-122 mean
__global__ void k_loss(const float* __restrict__ par, const unsigned* __restrict__ gm,
                       const int* __restrict__ cnt, float* __restrict__ out) {
    __shared__ float lb[NJ];
    int j = threadIdx.x;
    if (j < NJ) {
        float ls0 = par[P_LS0 + j], ls1 = par[P_LS1 + j];
        float m0 = __uint_as_float(gm[j]);
        float m1 = __uint_as_float(gm[NJ + j]);
        bool has = cnt[j] > 0;
        float lt0 = has ? m0 * m0 : ls0;
        float lt1 = has ? m1 * m1 : ls1;
        float whr = (ls0 + ls1) + (lt0 + lt1);
        float tr  = ls0 * lt0 + ls1 * lt1;
        float det_sqrt = sqrtf(fmaxf((ls0 * ls1) * (lt0 * lt1), FEPS));
        whr = whr - 2.f * sqrtf(fmaxf(tr + 2.f * det_sqrt, FEPS));
        float dist = sqrtf(fmaxf(whr, FEPS));
        float scale = 2.f * fmaxf(sqrtf(fmaxf(sqrtf(fmaxf(det_sqrt, FEPS)), FEPS)), FEPS);
        dist = dist / scale;
        lb[j] = 1.f - 1.f / (1.f + log1pf(dist));
    }
    __syncthreads();
    if (j == 0) {
        float total = 0.f;
        for (int t = 0; t < NJ; ++t) total += lb[t];
        // k = ceil(128*0.95) = 122 smallest  ==  total minus the 6 largest
        float topsum = 0.f;
        bool used[NJ];
        for (int t = 0; t < NJ; ++t) used[t] = false;
        for (int it = 0; it < NJ - 122; ++it) {
            float mx = -1e38f; int mi = 0;
            for (int t = 0; t < NJ; ++t)
                if (!used[t] && lb[t] > mx) { mx = lb[t]; mi = t; }
            used[mi] = true; topsum += mx;
        }
        out[0] = 1.0f * (total - topsum) / 122.f;   // LOSS_WEIGHT = 1
    }
}

// ---------------------------------------------------------------- launch
extern "C" void kernel_launch(void* const* d_in, const int* in_sizes, int n_in,
                              void* d_out, int out_size, void* d_ws, size_t ws_size,
                              hipStream_t stream) {
    const float* mu        = (const float*)d_in[0];
    const float* sigma     = (const float*)d_in[1];
    const int*   label     = (const int*)d_in[2];
    // d_in[3] = image: unused by the reference's forward pass
    const float* pos_thres = (const float*)d_in[4];
    const float* neg_thres = (const float*)d_in[5];
    float* out = (float*)d_out;

    // workspace layout
    float*    val = (float*)d_ws;                                   // 512*512 f32 (1 MiB)
    int*      vor = (int*)((char*)d_ws + (size_t)HH * WW * 4);      // 512*512 i32 (1 MiB)
    float*    par = (float*)((char*)d_ws + 2ull * HH * WW * 4);     // P_TOT f32
    unsigned* gm  = (unsigned*)(par + P_TOT);                       // 2*NJ u32
    int*      cnt = (int*)(gm + 2 * NJ);                            // NJ i32

    k_setup  <<<1, 128, 0, stream>>>(mu, sigma, par, gm, cnt);
    k_vor    <<<(HH * WW) / 256, 256, 0, stream>>>(par, val, vor);
    k_markers<<<(HF * WF) / 256, 256, 0, stream>>>(par, val, vor, mu, label,
                                                   pos_thres, neg_thres, gm, cnt);
    k_loss   <<<1, 128, 0, stream>>>(par, gm, cnt, out);
}

// Round 3
// 69.675 us; speedup vs baseline: 21.8908x; 21.8908x over previous
//
#include <hip/hip_runtime.h>
#include <math.h>

#define NJ 128
#define HH 512
#define WW 512
#define HF 1024
#define WF 1024
#define FEPS 1e-7f

// param layout offsets (in floats) inside `par`
#define P_MMX 0
#define P_MMY 128
#define P_IA  256
#define P_IB2 384
#define P_IC  512
#define P_V00 640
#define P_V10 768
#define P_V01 896
#define P_V11 1024
#define P_LS0 1152
#define P_LS1 1280
#define P_TOT 1408

// ---------------------------------------------------------------- K1: per-Gaussian params
__global__ void k_setup(const float* __restrict__ mu, const float* __restrict__ sigma,
                        float* __restrict__ par, unsigned* __restrict__ gm,
                        int* __restrict__ cnt) {
    int j = threadIdx.x;
    if (j >= NJ) return;
    float a = sigma[j * 4 + 0];
    float b = sigma[j * 4 + 1];
    float c = sigma[j * 4 + 3];
    // 2x2 symmetric eigendecomposition, ascending order (matches jnp.linalg.eigh)
    float mean = 0.5f * (a + c);
    float diff = 0.5f * (a - c);
    float disc = sqrtf(diff * diff + b * b);
    float l0 = mean - disc;   // smaller
    float l1 = mean + disc;   // larger
    // eigenvector for l1, picked for numerical robustness; sign is irrelevant
    float ux, uy;
    if (diff >= 0.f) { ux = diff + disc; uy = b; }
    else             { ux = b;           uy = disc - diff; }
    float nn = sqrtf(ux * ux + uy * uy);
    if (nn > 0.f) { ux /= nn; uy /= nn; } else { ux = 1.f; uy = 0.f; }
    // V columns: col0 <-> l0, col1 <-> l1
    float V00 = -uy, V10 = ux;   // column 0
    float V01 =  ux, V11 = uy;   // column 1
    // Lsc = Ld / sqrt(Ld0*Ld1) * 4096 ; sg = V diag(Lsc) V^T / 4
    float gmean = sqrtf(l0 * l1);
    float lsc0 = l0 / gmean * 4096.f;
    float lsc1 = l1 / gmean * 4096.f;
    float s00 = (V00 * V00 * lsc0 + V01 * V01 * lsc1) * 0.25f;
    float s01 = (V00 * V10 * lsc0 + V01 * V11 * lsc1) * 0.25f;
    float s11 = (V10 * V10 * lsc0 + V11 * V11 * lsc1) * 0.25f;
    float det = s00 * s11 - s01 * s01;
    float ia =  s11 / det;
    float ib = -s01 / det;
    float ic =  s00 / det;
    par[P_MMX + j] = rintf(mu[j * 2 + 0] * 0.5f);   // jnp.round = ties-to-even = rintf
    par[P_MMY + j] = rintf(mu[j * 2 + 1] * 0.5f);
    par[P_IA  + j] = ia;
    par[P_IB2 + j] = 2.f * ib;
    par[P_IC  + j] = ic;
    par[P_V00 + j] = V00; par[P_V10 + j] = V10;
    par[P_V01 + j] = V01; par[P_V11 + j] = V11;
    par[P_LS0 + j] = l0;  par[P_LS1 + j] = l1;
    gm[j] = 0u; gm[NJ + j] = 0u;   // |rot| >= 0, so uint-bit max with init 0 is exact
    cnt[j] = 0;
}

// ---------------------------------------------------------------- K2: half-res argmin maha
__global__ __launch_bounds__(256) void k_vor(const float* __restrict__ par,
                                             float* __restrict__ val,
                                             int* __restrict__ vor) {
    __shared__ float lds[640];
    int tid = threadIdx.x;
    for (int i = tid; i < 640; i += 256) lds[i] = par[i];
    __syncthreads();
    int p = blockIdx.x * 256 + tid;
    int r = p >> 9;     // row -> y
    int c = p & 511;    // col -> x
    const float SCALE = 512.0f / 511.0f;   // linspace(0, 512, 512) step
    float xc = (float)c * SCALE;
    float yr = (float)r * SCALE;
    float best = 3.4e38f;
    int bj = 0;
    #pragma unroll 8
    for (int j = 0; j < NJ; ++j) {
        float dx = xc - lds[P_MMX + j];
        float dy = yr - lds[P_MMY + j];
        float q = lds[P_IA + j] * dx * dx + lds[P_IB2 + j] * dx * dy
                + lds[P_IC + j] * dy * dy;
        if (q < best) { best = q; bj = j; }   // first-index on ties, like argmax(g)
    }
    val[p] = expf(-0.5f * best);
    vor[p] = bj;
}

// ---------------------------------------------------------------- K3: markers + segment max
__global__ __launch_bounds__(256) void k_markers(
        const float* __restrict__ par, const float* __restrict__ val,
        const int* __restrict__ vor, const float* __restrict__ mu,
        const int* __restrict__ label, const float* __restrict__ pos_thres,
        const float* __restrict__ neg_thres,
        unsigned* __restrict__ gm, int* __restrict__ cnt) {
    __shared__ unsigned lm[2 * NJ];
    __shared__ int lflag[NJ];
    int tid = threadIdx.x;
    if (tid < NJ) { lm[tid] = 0u; lm[NJ + tid] = 0u; lflag[tid] = 0; }
    __syncthreads();
    int p = blockIdx.x * 256 + tid;
    int i = p >> 10;    // row (y)
    int j = p & 1023;   // col (x)
    int hv = vor[(i >> 1) * WW + (j >> 1)];
    // exact-integer Laplacian (ones 3x3, center -8, zero-padded) on NN-upsampled vor
    int lap = -8 * hv;
    #pragma unroll
    for (int di = -1; di <= 1; ++di) {
        #pragma unroll
        for (int dj = -1; dj <= 1; ++dj) {
            if (di == 0 && dj == 0) continue;
            int ii = i + di, jj = j + dj;
            if (ii >= 0 && ii < HF && jj >= 0 && jj < WF)
                lap += vor[(ii >> 1) * WW + (jj >> 1)];
        }
    }
    bool ridge = (lap != 0);
    // align-corners bilinear of val: r = idx*511/1023
    float ry = ((float)i * 511.0f) / 1023.0f;
    float rx = ((float)j * 511.0f) / 1023.0f;
    int y0 = (int)floorf(ry); int y1 = min(y0 + 1, 511); float wy = ry - (float)y0;
    int x0 = (int)floorf(rx); int x1 = min(x0 + 1, 511); float wx = rx - (float)x0;
    float top = val[y0 * WW + x0] * (1.f - wx) + val[y0 * WW + x1] * wx;
    float bot = val[y1 * WW + x0] * (1.f - wx) + val[y1 * WW + x1] * wx;
    float vf  = top * (1.f - wy) + bot * wy;
    int cls = label[hv];
    int mk = hv + 1;
    if (vf < pos_thres[cls]) mk = 0;          // order matters: pos -> neg -> ridge
    if (vf < neg_thres[cls]) mk = NJ + 1;
    if (ridge)               mk = NJ + 1;
    if (mk >= 1 && mk <= NJ) {
        int inst = mk - 1;   // == hv here
        float dx = (float)j - mu[inst * 2 + 0];
        float dy = (float)i - mu[inst * 2 + 1];
        float r0 = fabsf(par[P_V00 + inst] * dx + par[P_V10 + inst] * dy);
        float r1 = fabsf(par[P_V01 + inst] * dx + par[P_V11 + inst] * dy);
        atomicMax(&lm[inst],      __float_as_uint(r0));
        atomicMax(&lm[NJ + inst], __float_as_uint(r1));
        lflag[inst] = 1;
    }
    __syncthreads();
    if (tid < NJ && lflag[tid]) {
        atomicMax(&gm[tid],      lm[tid]);
        atomicMax(&gm[NJ + tid], lm[NJ + tid]);
        cnt[tid] = 1;   // only >0 matters
    }
}

// ---------------------------------------------------------------- K4: loss + bottom-122 mean
// Fully parallel: LDS tree-sum for the total, then 6 rounds of LDS tree-argmax
// (knock out the winner with -inf). No scratch, no single-lane serial loops.
__global__ __launch_bounds__(128) void k_loss(
        const float* __restrict__ par, const unsigned* __restrict__ gm,
        const int* __restrict__ cnt, float* __restrict__ out) {
    __shared__ float lb[NJ];
    __shared__ float sv[NJ];
    __shared__ int   si[NJ];
    int j = threadIdx.x;

    float ls0 = par[P_LS0 + j], ls1 = par[P_LS1 + j];
    float m0 = __uint_as_float(gm[j]);
    float m1 = __uint_as_float(gm[NJ + j]);
    bool has = cnt[j] > 0;
    float lt0 = has ? m0 * m0 : ls0;
    float lt1 = has ? m1 * m1 : ls1;
    float whr = (ls0 + ls1) + (lt0 + lt1);
    float tr  = ls0 * lt0 + ls1 * lt1;
    float det_sqrt = sqrtf(fmaxf((ls0 * ls1) * (lt0 * lt1), FEPS));
    whr = whr - 2.f * sqrtf(fmaxf(tr + 2.f * det_sqrt, FEPS));
    float dist = sqrtf(fmaxf(whr, FEPS));
    float scale = 2.f * fmaxf(sqrtf(fmaxf(sqrtf(fmaxf(det_sqrt, FEPS)), FEPS)), FEPS);
    dist = dist / scale;
    float li = 1.f - 1.f / (1.f + log1pf(dist));
    lb[j] = li;
    sv[j] = li;
    __syncthreads();

    // total sum (tree over LDS)
    #pragma unroll
    for (int s = 64; s > 0; s >>= 1) {
        if (j < s) sv[j] += sv[j + s];
        __syncthreads();
    }
    float total = sv[0];   // every thread reads the same value post-barrier
    __syncthreads();

    // 6 largest (k = ceil(128*.95) = 122 smallest kept)
    float topsum = 0.f;
    #pragma unroll
    for (int it = 0; it < 6; ++it) {
        sv[j] = lb[j]; si[j] = j;
        __syncthreads();
        #pragma unroll
        for (int s = 64; s > 0; s >>= 1) {
            if (j < s) {
                if (sv[j + s] > sv[j]) { sv[j] = sv[j + s]; si[j] = si[j + s]; }
            }
            __syncthreads();
        }
        topsum += sv[0];
        if (j == 0) lb[si[0]] = -3.4e38f;
        __syncthreads();
    }

    if (j == 0) out[0] = 1.0f * (total - topsum) / 122.f;   // LOSS_WEIGHT = 1
}

// ---------------------------------------------------------------- launch
extern "C" void kernel_launch(void* const* d_in, const int* in_sizes, int n_in,
                              void* d_out, int out_size, void* d_ws, size_t ws_size,
                              hipStream_t stream) {
    const float* mu        = (const float*)d_in[0];
    const float* sigma     = (const float*)d_in[1];
    const int*   label     = (const int*)d_in[2];
    // d_in[3] = image: unused by the reference's forward pass
    const float* pos_thres = (const float*)d_in[4];
    const float* neg_thres = (const float*)d_in[5];
    float* out = (float*)d_out;

    // workspace layout
    float*    val = (float*)d_ws;                                   // 512*512 f32 (1 MiB)
    int*      vor = (int*)((char*)d_ws + (size_t)HH * WW * 4);      // 512*512 i32 (1 MiB)
    float*    par = (float*)((char*)d_ws + 2ull * HH * WW * 4);     // P_TOT f32
    unsigned* gm  = (unsigned*)(par + P_TOT);                       // 2*NJ u32
    int*      cnt = (int*)(gm + 2 * NJ);                            // NJ i32

    k_setup  <<<1, 128, 0, stream>>>(mu, sigma, par, gm, cnt);
    k_vor    <<<(HH * WW) / 256, 256, 0, stream>>>(par, val, vor);
    k_markers<<<(HF * WF) / 256, 256, 0, stream>>>(par, val, vor, mu, label,
                                                   pos_thres, neg_thres, gm, cnt);
    k_loss   <<<1, 128, 0, stream>>>(par, gm, cnt, out);
}